// Round 1
// baseline (782.936 us; speedup 1.0000x reference)
//
#include <hip/hip_runtime.h>
#include <hip/hip_bf16.h>

#define B_ 8
#define T_ 256
#define U_ 64
#define D_ 512
#define V_ 1024
#define M_ (B_*T_*U_)   // 131072

typedef __attribute__((ext_vector_type(8))) short bf16x8;
typedef __attribute__((ext_vector_type(4))) float f32x4;

__device__ __forceinline__ void gld_lds16(const void* g, void* l) {
    __builtin_amdgcn_global_load_lds(
        (const __attribute__((address_space(1))) void*)g,
        (__attribute__((address_space(3))) void*)l, 16, 0, 0);
}

// Convert W (V x D fp32, row-major) into bf16, pre-tiled k-major:
// Wt[((tileN*64 + k8)*128 + nl)*8 + e] = W[(tileN*128+nl)*512 + k8*8 + e]
// so each GEMM K-step's B tile is one contiguous 16 KB chunk whose
// lane-contiguous global_load_lds layout is conflict-free for B-frag reads.
__global__ void prep_kernel(const float* __restrict__ W,
                            const int* __restrict__ slen, const int* __restrict__ tlen,
                            __hip_bfloat16* __restrict__ Wt,
                            float* __restrict__ lenout) {
    int t = blockIdx.x * 256 + threadIdx.x;   // 65536 threads
    int n  = t >> 6;        // 0..1023
    int k8 = t & 63;        // 0..63
    const float4* p = (const float4*)(W + (size_t)n * D_ + k8 * 8);
    float4 a = p[0], c = p[1];
    union { __hip_bfloat16 h[8]; bf16x8 v; } u;
    u.h[0] = __float2bfloat16(a.x); u.h[1] = __float2bfloat16(a.y);
    u.h[2] = __float2bfloat16(a.z); u.h[3] = __float2bfloat16(a.w);
    u.h[4] = __float2bfloat16(c.x); u.h[5] = __float2bfloat16(c.y);
    u.h[6] = __float2bfloat16(c.z); u.h[7] = __float2bfloat16(c.w);
    int j = n >> 7, nl = n & 127;
    *(bf16x8*)(Wt + ((size_t)(j * 64 + k8) * 128 + nl) * 8) = u.v;
    if (blockIdx.x == 0 && threadIdx.x < 8) {
        lenout[threadIdx.x]     = (float)slen[threadIdx.x];
        lenout[8 + threadIdx.x] = (float)tlen[threadIdx.x];
    }
}

__device__ __forceinline__ bf16x8 pack_relu8(float4 s0, float4 s1, float4 g0, float4 g1) {
    union { __hip_bfloat16 h[8]; bf16x8 v; } u;
    u.h[0] = __float2bfloat16(fmaxf(s0.x + g0.x, 0.f));
    u.h[1] = __float2bfloat16(fmaxf(s0.y + g0.y, 0.f));
    u.h[2] = __float2bfloat16(fmaxf(s0.z + g0.z, 0.f));
    u.h[3] = __float2bfloat16(fmaxf(s0.w + g0.w, 0.f));
    u.h[4] = __float2bfloat16(fmaxf(s1.x + g1.x, 0.f));
    u.h[5] = __float2bfloat16(fmaxf(s1.y + g1.y, 0.f));
    u.h[6] = __float2bfloat16(fmaxf(s1.z + g1.z, 0.f));
    u.h[7] = __float2bfloat16(fmaxf(s1.w + g1.w, 0.f));
    return u.v;
}

// C[M,1024] = relu(src[b,t,:]+tgt[b,u,:]) @ W^T + bias
// 128x128 tile, BK=64. 4 waves, wave w owns block-local rows [w*32, w*32+32)
// x all 128 cols (2 row-frags x 8 col-frags of 16x16x32 bf16).
// A-fragment is computed DIRECTLY in registers (MFMA A layout is lane-local:
// row = lane&15, k = (lane>>4)*8..+7) -> no LDS for A, no A-staging barrier.
// B double-buffered in LDS with one-iteration prefetch distance (T3 2-phase):
// the vmcnt(0) drain at the single per-step barrier waits on a load issued a
// full iteration earlier -> latency hidden.
__global__ __launch_bounds__(256) void joiner_gemm(
    const float* __restrict__ src, const float* __restrict__ tgt,
    const __hip_bfloat16* __restrict__ Wt, const float* __restrict__ bias,
    float* __restrict__ out) {
    __shared__ __hip_bfloat16 Bs[2 * 8192];   // 32 KB, [buf][k8][n][8e]

    const int tid = threadIdx.x;
    // XCD-chunked swizzle: 8192 blocks, 8 XCDs, 8192%8==0 (bijective).
    // XCD x (= blockIdx%8) gets data-chunk x: tileM in [x*128,(x+1)*128) =
    // exactly batch b=x -> src 512KB + tgt 128KB + Wt 1MB resident in its L2.
    const int bx  = blockIdx.x;
    const int bid = (bx & 7) * 1024 + (bx >> 3);
    const int tileN = bid & 7;
    const int tileM = bid >> 3;
    const int m_base = tileM * 128;
    const int b  = m_base >> 14;            // T*U = 16384; tiles never straddle b
    const int t0 = (m_base & 16383) >> 6;   // rows 0..63 -> t0, 64..127 -> t0+1

    const int wid = tid >> 6, lane = tid & 63;
    const int lrow = lane & 15, lk = lane >> 4;

    // wave w: block-local rows w*32 + i*16 + lrow -> t = t0 + (w>>1), u = (w&1)*32 + i*16 + lrow
    const float* srcP  = src + (size_t)(b * T_ + t0 + (wid >> 1)) * D_;           // broadcast over lrow
    const float* tgtP0 = tgt + (size_t)(b * U_ + (wid & 1) * 32 + lrow) * D_;     // i = 0
    const float* tgtP1 = tgtP0 + 16 * D_;                                          // i = 1

    const __hip_bfloat16* WtT = Wt + (size_t)tileN * 64 * 128 * 8;
    // B-frag read base: element ((ks*4+lk)*128 + j*16 + lrow)*8
    const __hip_bfloat16* BsR = Bs + ((size_t)lk * 128 + lrow) * 8;

    f32x4 acc[2][8] = {};

    // prologue: stage kk=0 into buf 0 (16 KB, 16 wave-loads, 4 per wave)
    #pragma unroll
    for (int i = 0; i < 4; ++i) {
        const int wi = wid * 4 + i;                                   // wave-uniform
        gld_lds16(WtT + ((size_t)wi * 64 + lane) * 8, (void*)(Bs + wi * 512));
    }
    __syncthreads();

    #pragma unroll
    for (int kk = 0; kk < 8; ++kk) {
        const int cur = kk & 1;
        // ---- prefetch next B tile into the other buffer (drained at the
        //      barrier BELOW, i.e. one full iteration of cover)
        if (kk < 7) {
            const __hip_bfloat16* g = WtT + (size_t)(kk + 1) * 8192;
            __hip_bfloat16* dst = Bs + (cur ^ 1) * 8192;
            #pragma unroll
            for (int i = 0; i < 4; ++i) {
                const int wi = wid * 4 + i;
                gld_lds16(g + ((size_t)wi * 64 + lane) * 8, (void*)(dst + wi * 512));
            }
        }
        // ---- compute: A-frags in registers, B-frags from LDS, 32 MFMA
        const int kbase = kk * 64 + lk * 8;
        #pragma unroll
        for (int ks = 0; ks < 2; ++ks) {
            const int ko = kbase + ks * 32;
            float4 s0 = *(const float4*)(srcP + ko);
            float4 s1 = *(const float4*)(srcP + ko + 4);
            float4 ga = *(const float4*)(tgtP0 + ko);
            float4 gb = *(const float4*)(tgtP0 + ko + 4);
            float4 gc = *(const float4*)(tgtP1 + ko);
            float4 gd = *(const float4*)(tgtP1 + ko + 4);
            bf16x8 af0 = pack_relu8(s0, s1, ga, gb);   // row-frag i=0
            bf16x8 af1 = pack_relu8(s0, s1, gc, gd);   // row-frag i=1
            const __hip_bfloat16* br = BsR + cur * 8192 + ks * 4096;
            bf16x8 bfr[8];
            #pragma unroll
            for (int j = 0; j < 8; ++j)
                bfr[j] = *(const bf16x8*)(br + j * 128);
            #pragma unroll
            for (int j = 0; j < 8; ++j) {
                acc[0][j] = __builtin_amdgcn_mfma_f32_16x16x32_bf16(af0, bfr[j], acc[0][j], 0, 0, 0);
                acc[1][j] = __builtin_amdgcn_mfma_f32_16x16x32_bf16(af1, bfr[j], acc[1][j], 0, 0, 0);
            }
        }
        // single barrier per K-step: all reads of buf[cur] done, and the
        // vmcnt(0) drain completes the prefetch into buf[cur^1]
        if (kk != 7) __syncthreads();
    }

    // ---- epilogue: C/D layout col = lane&15, row = (lane>>4)*4 + reg
    const int n0 = tileN * 128;
    float bv[8];
    #pragma unroll
    for (int j = 0; j < 8; ++j) bv[j] = bias[n0 + j * 16 + lrow];
    const int mrow0 = m_base + wid * 32 + lk * 4;
    #pragma unroll
    for (int i = 0; i < 2; ++i) {
        #pragma unroll
        for (int r = 0; r < 4; ++r) {
            float* orow = out + (size_t)(mrow0 + i * 16 + r) * V_;
            #pragma unroll
            for (int j = 0; j < 8; ++j)
                orow[n0 + j * 16 + lrow] = acc[i][j][r] + bv[j];
        }
    }
}

extern "C" void kernel_launch(void* const* d_in, const int* in_sizes, int n_in,
                              void* d_out, int out_size, void* d_ws, size_t ws_size,
                              hipStream_t stream) {
    const float* src  = (const float*)d_in[0];
    const int*   slen = (const int*)d_in[1];
    const float* tgt  = (const float*)d_in[2];
    const int*   tlen = (const int*)d_in[3];
    const float* W    = (const float*)d_in[4];
    const float* bias = (const float*)d_in[5];
    float* out = (float*)d_out;
    __hip_bfloat16* Wt = (__hip_bfloat16*)d_ws;   // 1 MB

    prep_kernel<<<256, 256, 0, stream>>>(W, slen, tlen, Wt, out + (size_t)M_ * V_);
    joiner_gemm<<<M_ / 128 * (V_ / 128), 256, 0, stream>>>(src, tgt, Wt, bias, out);
}

// Round 2
// 778.928 us; speedup vs baseline: 1.0051x; 1.0051x over previous
//
#include <hip/hip_runtime.h>
#include <hip/hip_bf16.h>

#define B_ 8
#define T_ 256
#define U_ 64
#define D_ 512
#define V_ 1024
#define M_ (B_*T_*U_)   // 131072

typedef __attribute__((ext_vector_type(8))) short bf16x8;
typedef __attribute__((ext_vector_type(4))) float f32x4;

__device__ __forceinline__ void gld_lds16(const void* g, void* l) {
    __builtin_amdgcn_global_load_lds(
        (const __attribute__((address_space(1))) void*)g,
        (__attribute__((address_space(3))) void*)l, 16, 0, 0);
}

// Convert W (V x D fp32, row-major) into bf16, pre-tiled k-major:
// Wt[((tileN*64 + k8)*128 + nl)*8 + e] = W[(tileN*128+nl)*512 + k8*8 + e]
__global__ void prep_kernel(const float* __restrict__ W,
                            const int* __restrict__ slen, const int* __restrict__ tlen,
                            __hip_bfloat16* __restrict__ Wt,
                            float* __restrict__ lenout) {
    int t = blockIdx.x * 256 + threadIdx.x;   // 65536 threads
    int n  = t >> 6;        // 0..1023
    int k8 = t & 63;        // 0..63
    const float4* p = (const float4*)(W + (size_t)n * D_ + k8 * 8);
    float4 a = p[0], c = p[1];
    union { __hip_bfloat16 h[8]; bf16x8 v; } u;
    u.h[0] = __float2bfloat16(a.x); u.h[1] = __float2bfloat16(a.y);
    u.h[2] = __float2bfloat16(a.z); u.h[3] = __float2bfloat16(a.w);
    u.h[4] = __float2bfloat16(c.x); u.h[5] = __float2bfloat16(c.y);
    u.h[6] = __float2bfloat16(c.z); u.h[7] = __float2bfloat16(c.w);
    int j = n >> 7, nl = n & 127;
    *(bf16x8*)(Wt + ((size_t)(j * 64 + k8) * 128 + nl) * 8) = u.v;
    if (blockIdx.x == 0 && threadIdx.x < 8) {
        lenout[threadIdx.x]     = (float)slen[threadIdx.x];
        lenout[8 + threadIdx.x] = (float)tlen[threadIdx.x];
    }
}

__device__ __forceinline__ bf16x8 pack_relu8(float4 s0, float4 s1, float4 g0, float4 g1) {
    union { __hip_bfloat16 h[8]; bf16x8 v; } u;
    u.h[0] = __float2bfloat16(fmaxf(s0.x + g0.x, 0.f));
    u.h[1] = __float2bfloat16(fmaxf(s0.y + g0.y, 0.f));
    u.h[2] = __float2bfloat16(fmaxf(s0.z + g0.z, 0.f));
    u.h[3] = __float2bfloat16(fmaxf(s0.w + g0.w, 0.f));
    u.h[4] = __float2bfloat16(fmaxf(s1.x + g1.x, 0.f));
    u.h[5] = __float2bfloat16(fmaxf(s1.y + g1.y, 0.f));
    u.h[6] = __float2bfloat16(fmaxf(s1.z + g1.z, 0.f));
    u.h[7] = __float2bfloat16(fmaxf(s1.w + g1.w, 0.f));
    return u.v;
}

// C[M,1024] = relu(src[b,t,:]+tgt[b,u,:]) @ W^T + bias
// 128x128 tile, BK=64. Wave w owns block-local rows [w*32,w*32+32) x 128 cols.
// A-operand is software-pipelined ONE KK AHEAD in registers:
//   top of kk:    issue 12 float4 A-loads (kk+1) FIRST, then 16 gld_lds B(kk+1)
//   compute kk:   register A-frags (packed last iter) + LDS B-frags -> 32 MFMA,
//                 ZERO vmem waits on the critical path
//   bottom of kk: pack kk+1 A-frags (vmcnt wait leaves the NEWER gld_lds in
//                 flight - vmcnt is in-order, A-loads are OLDER), then one
//                 __syncthreads whose vmcnt(0) drain lands ~600cy after issue.
__global__ __launch_bounds__(256) void joiner_gemm(
    const float* __restrict__ src, const float* __restrict__ tgt,
    const __hip_bfloat16* __restrict__ Wt, const float* __restrict__ bias,
    float* __restrict__ out) {
    __shared__ __hip_bfloat16 Bs[2 * 8192];   // 32 KB, [buf][k8][n][8e]

    const int tid = threadIdx.x;
    // XCD-chunked swizzle (8192 % 8 == 0, bijective): XCD x gets batch b=x,
    // so src(512K)+tgt(128K)+Wt(1M) stay resident in that XCD's 4MB L2.
    const int bx  = blockIdx.x;
    const int bid = (bx & 7) * 1024 + (bx >> 3);
    const int tileN = bid & 7;
    const int tileM = bid >> 3;
    const int m_base = tileM * 128;
    const int b  = m_base >> 14;            // T*U = 16384; tiles never straddle b
    const int t0 = (m_base & 16383) >> 6;

    const int wid = tid >> 6, lane = tid & 63;
    const int lrow = lane & 15, lk = lane >> 4;

    // A-frag layout (verified): row = lane&15, k = kk*64 + ks*32 + lk*8 + e
    const float* srcP  = src + (size_t)(b * T_ + t0 + (wid >> 1)) * D_ + lk * 8;
    const float* tgtP0 = tgt + (size_t)(b * U_ + (wid & 1) * 32 + lrow) * D_ + lk * 8;
    const float* tgtP1 = tgtP0 + 16 * D_;

    const __hip_bfloat16* WtT = Wt + (size_t)tileN * 64 * 128 * 8;
    const __hip_bfloat16* BsR = Bs + ((size_t)lk * 128 + lrow) * 8;

    f32x4 acc[2][8] = {};
    float4 ld[12];
    bf16x8 afc[2][2];   // [ks][row-frag i], always compile-time indexed

#define LOADA(koff)                                                   \
    ld[0]  = *(const float4*)(srcP  + (koff));                        \
    ld[1]  = *(const float4*)(srcP  + (koff) + 4);                    \
    ld[2]  = *(const float4*)(tgtP0 + (koff));                        \
    ld[3]  = *(const float4*)(tgtP0 + (koff) + 4);                    \
    ld[4]  = *(const float4*)(tgtP1 + (koff));                        \
    ld[5]  = *(const float4*)(tgtP1 + (koff) + 4);                    \
    ld[6]  = *(const float4*)(srcP  + (koff) + 32);                   \
    ld[7]  = *(const float4*)(srcP  + (koff) + 36);                   \
    ld[8]  = *(const float4*)(tgtP0 + (koff) + 32);                   \
    ld[9]  = *(const float4*)(tgtP0 + (koff) + 36);                   \
    ld[10] = *(const float4*)(tgtP1 + (koff) + 32);                   \
    ld[11] = *(const float4*)(tgtP1 + (koff) + 36);

#define PACKA()                                                       \
    afc[0][0] = pack_relu8(ld[0], ld[1], ld[2],  ld[3]);              \
    afc[0][1] = pack_relu8(ld[0], ld[1], ld[4],  ld[5]);              \
    afc[1][0] = pack_relu8(ld[6], ld[7], ld[8],  ld[9]);              \
    afc[1][1] = pack_relu8(ld[6], ld[7], ld[10], ld[11]);

    // ---- prologue: A(kk=0) loads, B(kk=0) prefetch, pack, sync
    LOADA(0)
    #pragma unroll
    for (int i = 0; i < 4; ++i) {
        const int wi = wid * 4 + i;                                   // wave-uniform
        gld_lds16(WtT + ((size_t)wi * 64 + lane) * 8, (void*)(Bs + wi * 512));
    }
    PACKA()
    __syncthreads();

    #pragma unroll
    for (int kk = 0; kk < 8; ++kk) {
        const int cur = kk & 1;
        if (kk < 7) {
            // A-loads FIRST (older in vmcnt order), then B prefetch
            LOADA((kk + 1) * 64)
            const __hip_bfloat16* g = WtT + (size_t)(kk + 1) * 8192;
            __hip_bfloat16* dst = Bs + (cur ^ 1) * 8192;
            #pragma unroll
            for (int i = 0; i < 4; ++i) {
                const int wi = wid * 4 + i;
                gld_lds16(g + ((size_t)wi * 64 + lane) * 8, (void*)(dst + wi * 512));
            }
            __builtin_amdgcn_sched_barrier(0);   // pin: loads stay issued up here
        }
        // ---- compute kk: register A-frags, LDS B-frags, 32 MFMA
        #pragma unroll
        for (int ks = 0; ks < 2; ++ks) {
            const __hip_bfloat16* br = BsR + cur * 8192 + ks * 4096;
            bf16x8 bfr[8];
            #pragma unroll
            for (int j = 0; j < 8; ++j)
                bfr[j] = *(const bf16x8*)(br + j * 128);
            #pragma unroll
            for (int j = 0; j < 8; ++j) {
                acc[0][j] = __builtin_amdgcn_mfma_f32_16x16x32_bf16(afc[ks][0], bfr[j], acc[0][j], 0, 0, 0);
                acc[1][j] = __builtin_amdgcn_mfma_f32_16x16x32_bf16(afc[ks][1], bfr[j], acc[1][j], 0, 0, 0);
            }
        }
        if (kk < 7) {
            // pack kk+1 frags: waits A-loads (vmcnt leaves gld_lds in flight);
            // old afc values were consumed by the MFMAs above.
            PACKA()
            __syncthreads();   // vmcnt(0) drain: gld_lds issued ~600cy earlier
        }
    }
#undef LOADA
#undef PACKA

    // ---- epilogue: C/D layout col = lane&15, row = (lane>>4)*4 + reg
    const int n0 = tileN * 128;
    float bv[8];
    #pragma unroll
    for (int j = 0; j < 8; ++j) bv[j] = bias[n0 + j * 16 + lrow];
    const int mrow0 = m_base + wid * 32 + lk * 4;
    #pragma unroll
    for (int i = 0; i < 2; ++i) {
        #pragma unroll
        for (int r = 0; r < 4; ++r) {
            float* orow = out + (size_t)(mrow0 + i * 16 + r) * V_;
            #pragma unroll
            for (int j = 0; j < 8; ++j)
                orow[n0 + j * 16 + lrow] = acc[i][j][r] + bv[j];
        }
    }
}

extern "C" void kernel_launch(void* const* d_in, const int* in_sizes, int n_in,
                              void* d_out, int out_size, void* d_ws, size_t ws_size,
                              hipStream_t stream) {
    const float* src  = (const float*)d_in[0];
    const int*   slen = (const int*)d_in[1];
    const float* tgt  = (const float*)d_in[2];
    const int*   tlen = (const int*)d_in[3];
    const float* W    = (const float*)d_in[4];
    const float* bias = (const float*)d_in[5];
    float* out = (float*)d_out;
    __hip_bfloat16* Wt = (__hip_bfloat16*)d_ws;   // 1 MB

    prep_kernel<<<256, 256, 0, stream>>>(W, slen, tlen, Wt, out + (size_t)M_ * V_);
    joiner_gemm<<<M_ / 128 * (V_ / 128), 256, 0, stream>>>(src, tgt, Wt, bias, out);
}

// Round 3
// 734.280 us; speedup vs baseline: 1.0663x; 1.0608x over previous
//
#include <hip/hip_runtime.h>
#include <hip/hip_bf16.h>

#define B_ 8
#define T_ 256
#define U_ 64
#define D_ 512
#define V_ 1024
#define M_ (B_*T_*U_)   // 131072

typedef __attribute__((ext_vector_type(8))) short bf16x8;
typedef __attribute__((ext_vector_type(4))) float f32x4;

__device__ __forceinline__ void gld_lds16(const void* g, void* l) {
    __builtin_amdgcn_global_load_lds(
        (const __attribute__((address_space(1))) void*)g,
        (__attribute__((address_space(3))) void*)l, 16, 0, 0);
}

// Convert W (V x D fp32, row-major) into bf16, pre-tiled k-major:
// Wt[((tileN*64 + k8)*128 + nl)*8 + e] = W[(tileN*128+nl)*512 + k8*8 + e]
__global__ void prep_kernel(const float* __restrict__ W,
                            const int* __restrict__ slen, const int* __restrict__ tlen,
                            __hip_bfloat16* __restrict__ Wt,
                            float* __restrict__ lenout) {
    int t = blockIdx.x * 256 + threadIdx.x;   // 65536 threads
    int n  = t >> 6;        // 0..1023
    int k8 = t & 63;        // 0..63
    const float4* p = (const float4*)(W + (size_t)n * D_ + k8 * 8);
    float4 a = p[0], c = p[1];
    union { __hip_bfloat16 h[8]; bf16x8 v; } u;
    u.h[0] = __float2bfloat16(a.x); u.h[1] = __float2bfloat16(a.y);
    u.h[2] = __float2bfloat16(a.z); u.h[3] = __float2bfloat16(a.w);
    u.h[4] = __float2bfloat16(c.x); u.h[5] = __float2bfloat16(c.y);
    u.h[6] = __float2bfloat16(c.z); u.h[7] = __float2bfloat16(c.w);
    int j = n >> 7, nl = n & 127;
    *(bf16x8*)(Wt + ((size_t)(j * 64 + k8) * 128 + nl) * 8) = u.v;
    if (blockIdx.x == 0 && threadIdx.x < 8) {
        lenout[threadIdx.x]     = (float)slen[threadIdx.x];
        lenout[8 + threadIdx.x] = (float)tlen[threadIdx.x];
    }
}

__device__ __forceinline__ bf16x8 pack_relu8(float4 s0, float4 s1, float4 g0, float4 g1) {
    union { __hip_bfloat16 h[8]; bf16x8 v; } u;
    u.h[0] = __float2bfloat16(fmaxf(s0.x + g0.x, 0.f));
    u.h[1] = __float2bfloat16(fmaxf(s0.y + g0.y, 0.f));
    u.h[2] = __float2bfloat16(fmaxf(s0.z + g0.z, 0.f));
    u.h[3] = __float2bfloat16(fmaxf(s0.w + g0.w, 0.f));
    u.h[4] = __float2bfloat16(fmaxf(s1.x + g1.x, 0.f));
    u.h[5] = __float2bfloat16(fmaxf(s1.y + g1.y, 0.f));
    u.h[6] = __float2bfloat16(fmaxf(s1.z + g1.z, 0.f));
    u.h[7] = __float2bfloat16(fmaxf(s1.w + g1.w, 0.f));
    return u.v;
}

// C[M,1024] = relu(src[b,t,:]+tgt[b,u,:]) @ W^T + bias
// 128x128 tile (2 t-rows x 64 u-rows), BK=64, 8 K-steps.
// KEY CHANGE vs r2: the tgt operand is no longer per-lane GATHERED from
// global (32 L1 lines / instruction was the TA-transaction bottleneck).
// Per kk we stage the 64u x 64k f32 tgt panel into LDS with global_load_lds
// whose per-lane SOURCE addresses are dense (16 packed lines / 1024B chunk).
// LDS row stride padded to 272B (68 floats): bank shift 4/row -> 8 rows tile
// all 32 banks -> A-frag ds_read_b128 is a uniform free 2-way.
// src (2 rows) stays as register broadcasts. B path unchanged (dbuf gld_lds).
__global__ __launch_bounds__(256, 3) void joiner_gemm(
    const float* __restrict__ src, const float* __restrict__ tgt,
    const __hip_bfloat16* __restrict__ Wt, const float* __restrict__ bias,
    float* __restrict__ out) {
    __shared__ __align__(16) __hip_bfloat16 Bs[2 * 8192];  // 32 KB [buf][k8][n][8e]
    __shared__ __align__(16) float Tg[64 * 68];            // 17 KB, 272B row stride

    const int tid = threadIdx.x;
    // XCD-chunked swizzle (8192 % 8 == 0, bijective): XCD x gets batch b=x.
    const int bx  = blockIdx.x;
    const int bid = (bx & 7) * 1024 + (bx >> 3);
    const int tileN = bid & 7;
    const int tileM = bid >> 3;
    const int m_base = tileM * 128;
    const int b  = m_base >> 14;            // tiles never straddle b
    const int t0 = (m_base & 16383) >> 6;

    const int wid = tid >> 6, lane = tid & 63;
    const int lrow = lane & 15, lk = lane >> 4;

    // src broadcast pointer: A-frag k = kk*64 + ks*32 + lk*8 + e, row-independent
    const float* srcP = src + (size_t)(b * T_ + t0 + (wid >> 1)) * D_ + lk * 8;

    // ---- tgt staging source pointers. Chunk c writes LDS bytes [c*1024,+1024).
    // 16B-granule index s16 = c*64 + lane -> u = s16/17, slot = s16%17
    // (17 granules per 272B row; slot 16 is the pad granule -> clamp, unused).
    // 17408B / 1024 = 17 chunks: waves take 4 each, wave 0 takes chunk 16 too.
    const float* tgGp[5];
    #pragma unroll
    for (int i = 0; i < 5; ++i) {
        const int c   = (i < 4) ? (wid * 4 + i) : 16;
        const int s16 = c * 64 + lane;
        const int u   = (s16 * 241) >> 12;      // exact s16/17 for s16<=1087
        int slot = s16 - u * 17;
        if (slot == 16) slot = 0;               // pad granule: load safe dup
        tgGp[i] = tgt + (size_t)(b * U_ + u) * D_ + slot * 4;
    }

    const __hip_bfloat16* WtT = Wt + (size_t)tileN * 64 * 128 * 8;
    const __hip_bfloat16* BsR = Bs + ((size_t)lk * 128 + lrow) * 8;
    char* TgB = (char*)Tg;
    const int wq = (wid & 1) * 32;              // wave's u-base (waves 0,2 / 1,3)

    f32x4 acc[2][8] = {};
    bf16x8 afc[2][2];
    float4 c0a, c0b, c1a, c1b, n0a, n0b, n1a, n1b;

#define STAGE(kkn, bbuf) { \
    _Pragma("unroll") \
    for (int i = 0; i < 4; ++i) { \
        const int c = wid * 4 + i; \
        gld_lds16(tgGp[i] + (kkn) * 64, (void*)(TgB + c * 1024)); \
        gld_lds16(WtT + (size_t)(kkn) * 8192 + ((size_t)c * 64 + lane) * 8, \
                  (void*)(Bs + (bbuf) * 8192 + c * 512)); \
    } \
    if (wid == 0) gld_lds16(tgGp[4] + (kkn) * 64, (void*)(TgB + 16 * 1024)); }

    // ---- prologue: stage kk=0 (Tg + Bs[0]), src regs kk=0
    STAGE(0, 0)
    c0a = *(const float4*)(srcP + 0);  c0b = *(const float4*)(srcP + 4);
    c1a = *(const float4*)(srcP + 32); c1b = *(const float4*)(srcP + 36);
    __syncthreads();

    #pragma unroll
    for (int kk = 0; kk < 8; ++kk) {
        const int cur = kk & 1;
        // ---- assemble A-frags: tgt from padded LDS + src regs (all f32 adds)
        #pragma unroll
        for (int i = 0; i < 2; ++i) {
            const int rowb = (wq + i * 16 + lrow) * 272;
            {   // ks = 0: k_local = lk*8
                const float4 ta = *(const float4*)(TgB + rowb + lk * 32);
                const float4 tb = *(const float4*)(TgB + rowb + lk * 32 + 16);
                afc[0][i] = pack_relu8(c0a, c0b, ta, tb);
            }
            {   // ks = 1: k_local = 32 + lk*8
                const float4 ta = *(const float4*)(TgB + rowb + 128 + lk * 32);
                const float4 tb = *(const float4*)(TgB + rowb + 128 + lk * 32 + 16);
                afc[1][i] = pack_relu8(c1a, c1b, ta, tb);
            }
        }
        __syncthreads();          // #1: Tg consumed. vmcnt queue is empty -> cheap.
        if (kk < 7) {
            const int ko = (kk + 1) * 64;
            n0a = *(const float4*)(srcP + ko);      n0b = *(const float4*)(srcP + ko + 4);
            n1a = *(const float4*)(srcP + ko + 32); n1b = *(const float4*)(srcP + ko + 36);
            STAGE(kk + 1, cur ^ 1)   // overwrites Tg + fills Bs[cur^1]
        }
        // ---- MFMA: B frags from Bs[cur] (staged last iter, drained at #2)
        #pragma unroll
        for (int ks = 0; ks < 2; ++ks) {
            const __hip_bfloat16* br = BsR + cur * 8192 + ks * 4096;
            bf16x8 bfr[8];
            #pragma unroll
            for (int j = 0; j < 8; ++j)
                bfr[j] = *(const bf16x8*)(br + j * 128);
            #pragma unroll
            for (int j = 0; j < 8; ++j) {
                acc[0][j] = __builtin_amdgcn_mfma_f32_16x16x32_bf16(afc[ks][0], bfr[j], acc[0][j], 0, 0, 0);
                acc[1][j] = __builtin_amdgcn_mfma_f32_16x16x32_bf16(afc[ks][1], bfr[j], acc[1][j], 0, 0, 0);
            }
        }
        if (kk < 7) {
            c0a = n0a; c0b = n0b; c1a = n1a; c1b = n1b;
            __syncthreads();      // #2: vmcnt(0) drain covered by 32 MFMA + 16 ds_read
        }
    }
#undef STAGE

    // ---- epilogue: C/D layout col = lane&15, row = (lane>>4)*4 + reg
    const int n0 = tileN * 128;
    float bv[8];
    #pragma unroll
    for (int j = 0; j < 8; ++j) bv[j] = bias[n0 + j * 16 + lrow];
    const int mrow0 = m_base + wid * 32 + lk * 4;
    #pragma unroll
    for (int i = 0; i < 2; ++i) {
        #pragma unroll
        for (int r = 0; r < 4; ++r) {
            float* orow = out + (size_t)(mrow0 + i * 16 + r) * V_;
            #pragma unroll
            for (int j = 0; j < 8; ++j)
                orow[n0 + j * 16 + lrow] = acc[i][j][r] + bv[j];
        }
    }
}

extern "C" void kernel_launch(void* const* d_in, const int* in_sizes, int n_in,
                              void* d_out, int out_size, void* d_ws, size_t ws_size,
                              hipStream_t stream) {
    const float* src  = (const float*)d_in[0];
    const int*   slen = (const int*)d_in[1];
    const float* tgt  = (const float*)d_in[2];
    const int*   tlen = (const int*)d_in[3];
    const float* W    = (const float*)d_in[4];
    const float* bias = (const float*)d_in[5];
    float* out = (float*)d_out;
    __hip_bfloat16* Wt = (__hip_bfloat16*)d_ws;   // 1 MB

    prep_kernel<<<256, 256, 0, stream>>>(W, slen, tlen, Wt, out + (size_t)M_ * V_);
    joiner_gemm<<<M_ / 128 * (V_ / 128), 256, 0, stream>>>(src, tgt, Wt, bias, out);
}

// Round 4
// 651.698 us; speedup vs baseline: 1.2014x; 1.1267x over previous
//
#include <hip/hip_runtime.h>
#include <hip/hip_bf16.h>

#define B_ 8
#define T_ 256
#define U_ 64
#define D_ 512
#define V_ 1024
#define M_ (B_*T_*U_)   // 131072

typedef __attribute__((ext_vector_type(8))) short bf16x8;
typedef __attribute__((ext_vector_type(4))) float f32x4;

__device__ __forceinline__ void gld_lds16(const void* g, void* l) {
    __builtin_amdgcn_global_load_lds(
        (const __attribute__((address_space(1))) void*)g,
        (__attribute__((address_space(3))) void*)l, 16, 0, 0);
}

// Convert W (V x D fp32, row-major) into bf16, pre-tiled k-major for 256-wide
// N-tiles: Wt[((tileN*64 + k8)*256 + nl)*8 + e] = W[(tileN*256+nl)*512 + k8*8 + e]
// Each GEMM K-step's B tile is one contiguous 32 KB chunk whose lane-contiguous
// global_load_lds layout is conflict-free for B-frag reads.
__global__ void prep_kernel(const float* __restrict__ W,
                            const int* __restrict__ slen, const int* __restrict__ tlen,
                            __hip_bfloat16* __restrict__ Wt,
                            float* __restrict__ lenout) {
    int t = blockIdx.x * 256 + threadIdx.x;   // 65536 threads
    int n  = t >> 6;        // 0..1023
    int k8 = t & 63;        // 0..63
    const float4* p = (const float4*)(W + (size_t)n * D_ + k8 * 8);
    float4 a = p[0], c = p[1];
    union { __hip_bfloat16 h[8]; bf16x8 v; } u;
    u.h[0] = __float2bfloat16(a.x); u.h[1] = __float2bfloat16(a.y);
    u.h[2] = __float2bfloat16(a.z); u.h[3] = __float2bfloat16(a.w);
    u.h[4] = __float2bfloat16(c.x); u.h[5] = __float2bfloat16(c.y);
    u.h[6] = __float2bfloat16(c.z); u.h[7] = __float2bfloat16(c.w);
    int j = n >> 8, nl = n & 255;   // 4 N-tiles of 256
    *(bf16x8*)(Wt + ((size_t)(j * 64 + k8) * 256 + nl) * 8) = u.v;
    if (blockIdx.x == 0 && threadIdx.x < 8) {
        lenout[threadIdx.x]     = (float)slen[threadIdx.x];
        lenout[8 + threadIdx.x] = (float)tlen[threadIdx.x];
    }
}

__device__ __forceinline__ void relu_store8(__hip_bfloat16* dst,
                                            float4 a, float4 a2, float4 b, float4 b2) {
    union { __hip_bfloat16 h[8]; bf16x8 v; } u;
    u.h[0] = __float2bfloat16(fmaxf(a.x  + b.x,  0.f));
    u.h[1] = __float2bfloat16(fmaxf(a.y  + b.y,  0.f));
    u.h[2] = __float2bfloat16(fmaxf(a.z  + b.z,  0.f));
    u.h[3] = __float2bfloat16(fmaxf(a.w  + b.w,  0.f));
    u.h[4] = __float2bfloat16(fmaxf(a2.x + b2.x, 0.f));
    u.h[5] = __float2bfloat16(fmaxf(a2.y + b2.y, 0.f));
    u.h[6] = __float2bfloat16(fmaxf(a2.z + b2.z, 0.f));
    u.h[7] = __float2bfloat16(fmaxf(a2.w + b2.w, 0.f));
    *(bf16x8*)dst = u.v;
}

// C[M,1024] = relu(src[b,t,:]+tgt[b,u,:]) @ W^T + bias
// SCALED r0 structure: 128x256 tile, BK=64, 512 threads = 8 waves (2M x 4N),
// each wave a 64x64 sub-tile (4x4 MFMA frags -> A and B frags each reused 4x,
// 0.5 KB LDS-read per MFMA). Same proven 2-barrier K-loop as the 655.8 us
// session kernel; vs that kernel this halves B-staging traffic per output
// column, halves barriers per MFMA, and cuts vmem line-requests ~35%.
__global__ __launch_bounds__(512) void joiner_gemm(
    const float* __restrict__ src, const float* __restrict__ tgt,
    const __hip_bfloat16* __restrict__ Wt, const float* __restrict__ bias,
    float* __restrict__ out) {
    // A: 128 rows x 64 k, padded stride 72 bf16 (proven conflict-free)
    __shared__ __align__(16) __hip_bfloat16 As[128 * 72];   // 18 KB
    // B: k-major [k8][n=256][8e], matches gld_lds lane-contiguous layout
    __shared__ __align__(16) __hip_bfloat16 Bs[8 * 256 * 8]; // 32 KB

    const int tid = threadIdx.x;
    const int bx  = blockIdx.x;           // 4096 blocks, no swizzle (r0 had none)
    const int tileN = bx & 3;
    const int tileM = bx >> 2;
    const int m_base = tileM * 128;
    const int b  = m_base >> 14;          // T*U = 16384; tiles never straddle b
    const int t0 = (m_base & 16383) >> 6; // rows 0..63 -> t0, 64..127 -> t0+1

    // A-staging coords: thread stages rows r0 (t0,u=r0) and r0+64 (t0+1,u=r0)
    const int r0 = tid >> 3;              // 0..63  (= u)
    const int kc = (tid & 7) * 8;         // 0..56
    const float* srcA = src + (size_t)(b * T_ + t0) * D_ + kc;
    const float* srcB = srcA + D_;                       // t0+1
    const float* tgtA = tgt + (size_t)(b * U_ + r0) * D_ + kc;
    __hip_bfloat16* As0 = As + r0 * 72 + kc;

    const __hip_bfloat16* WtT = Wt + (size_t)tileN * 64 * 256 * 8;

    const int wid  = tid >> 6, lane = tid & 63;
    const int waveM = wid >> 2, waveN = wid & 3;
    const int lrow = lane & 15, lk = lane >> 4;
    const __hip_bfloat16* AsW = As + (waveM * 64 + lrow) * 72 + lk * 8;
    const __hip_bfloat16* BsW = Bs + ((size_t)lk * 256 + waveN * 64 + lrow) * 8;

    f32x4 acc[4][4] = {};

    for (int kk = 0; kk < 8; ++kk) {
        // ---- stage B: 32 KB contiguous chunk via async global->LDS (16 B/lane)
        const __hip_bfloat16* gB = WtT + (size_t)kk * 16384;
        #pragma unroll
        for (int i = 0; i < 4; ++i) {
            const int c = wid * 4 + i;                       // wave-uniform 0..31
            gld_lds16(gB + ((size_t)c * 64 + lane) * 8, (void*)(Bs + c * 512));
        }
        // ---- stage A: relu(src+tgt) -> bf16 -> LDS (6 loads feed 2 rows)
        const int ko = kk * 64;
        float4 s0  = *(const float4*)(srcA + ko);
        float4 s0b = *(const float4*)(srcA + ko + 4);
        float4 s1  = *(const float4*)(srcB + ko);
        float4 s1b = *(const float4*)(srcB + ko + 4);
        float4 g0  = *(const float4*)(tgtA + ko);
        float4 g0b = *(const float4*)(tgtA + ko + 4);
        relu_store8(As0,           s0, s0b, g0, g0b);   // row r0     (t0,   u=r0)
        relu_store8(As0 + 64 * 72, s1, s1b, g0, g0b);   // row r0+64  (t0+1, u=r0)

        __syncthreads();   // drains gld_lds + ds_writes (compiler-inserted cnt)

        #pragma unroll
        for (int ks = 0; ks < 2; ++ks) {
            bf16x8 af[4], bfr[4];
            #pragma unroll
            for (int i = 0; i < 4; ++i)
                af[i] = *(const bf16x8*)(AsW + i * 16 * 72 + ks * 32);
            #pragma unroll
            for (int j = 0; j < 4; ++j)
                bfr[j] = *(const bf16x8*)(BsW + ks * 8192 + j * 128);
            #pragma unroll
            for (int i = 0; i < 4; ++i)
                #pragma unroll
                for (int j = 0; j < 4; ++j)
                    acc[i][j] = __builtin_amdgcn_mfma_f32_16x16x32_bf16(
                        af[i], bfr[j], acc[i][j], 0, 0, 0);
        }
        if (kk != 7) __syncthreads();   // WAR: next kk overwrites As/Bs
    }

    // ---- epilogue: C/D layout col = lane&15, row = (lane>>4)*4 + reg
    const int n0 = tileN * 256 + waveN * 64;
    float bv[4];
    #pragma unroll
    for (int j = 0; j < 4; ++j) bv[j] = bias[n0 + j * 16 + lrow];
    #pragma unroll
    for (int i = 0; i < 4; ++i) {
        const int mrow = m_base + waveM * 64 + i * 16 + lk * 4;
        #pragma unroll
        for (int r = 0; r < 4; ++r) {
            float* orow = out + (size_t)(mrow + r) * V_;
            #pragma unroll
            for (int j = 0; j < 4; ++j)
                orow[n0 + j * 16 + lrow] = acc[i][j][r] + bv[j];
        }
    }
}

extern "C" void kernel_launch(void* const* d_in, const int* in_sizes, int n_in,
                              void* d_out, int out_size, void* d_ws, size_t ws_size,
                              hipStream_t stream) {
    const float* src  = (const float*)d_in[0];
    const int*   slen = (const int*)d_in[1];
    const float* tgt  = (const float*)d_in[2];
    const int*   tlen = (const int*)d_in[3];
    const float* W    = (const float*)d_in[4];
    const float* bias = (const float*)d_in[5];
    float* out = (float*)d_out;
    __hip_bfloat16* Wt = (__hip_bfloat16*)d_ws;   // 1 MB

    prep_kernel<<<256, 256, 0, stream>>>(W, slen, tlen, Wt, out + (size_t)M_ * V_);
    joiner_gemm<<<(M_ / 128) * (V_ / 256), 512, 0, stream>>>(src, tgt, Wt, bias, out);
}